// Round 1
// baseline (537.491 us; speedup 1.0000x reference)
//
#include <hip/hip_runtime.h>

// GCN: out = dinv ⊙ ( A_sum ( dinv ⊙ (x@W) ) ) + b, A_sum includes self-loop.
// CSR (by dst) built on-device each call; pull-based aggregation (no float atomics).

__global__ __launch_bounds__(256) void k_count(const int* __restrict__ dst, int E,
                                               int* __restrict__ counts) {
    int e = blockIdx.x * 256 + threadIdx.x;
    if (e < E) atomicAdd(&counts[dst[e]], 1);
}

__global__ __launch_bounds__(256) void k_dinv(const int* __restrict__ counts, int N,
                                              float* __restrict__ dinv) {
    int i = blockIdx.x * 256 + threadIdx.x;
    if (i < N) dinv[i] = rsqrtf((float)(counts[i] + 1));  // +1 self-loop; always > 0
}

__global__ __launch_bounds__(256) void k_scanA(const int* __restrict__ counts, int N,
                                               int* __restrict__ bsum) {
    __shared__ int s[256];
    int i = blockIdx.x * 256 + threadIdx.x;
    s[threadIdx.x] = (i < N) ? counts[i] : 0;
    __syncthreads();
    for (int off = 128; off > 0; off >>= 1) {
        if (threadIdx.x < off) s[threadIdx.x] += s[threadIdx.x + off];
        __syncthreads();
    }
    if (threadIdx.x == 0) bsum[blockIdx.x] = s[0];
}

__global__ __launch_bounds__(256) void k_scanB(const int* __restrict__ bsum, int nb,
                                               int* __restrict__ boff) {
    __shared__ int s[256];
    int tid = threadIdx.x;
    int v = (tid < nb) ? bsum[tid] : 0;
    s[tid] = v;
    __syncthreads();
    for (int off = 1; off < 256; off <<= 1) {
        int t = (tid >= off) ? s[tid - off] : 0;
        __syncthreads();
        s[tid] += t;
        __syncthreads();
    }
    if (tid < nb) boff[tid] = s[tid] - v;  // exclusive
}

__global__ __launch_bounds__(256) void k_scanC(const int* __restrict__ counts, int N,
                                               const int* __restrict__ boff,
                                               int* __restrict__ row_ptr,
                                               int* __restrict__ cursor) {
    __shared__ int s[256];
    int tid = threadIdx.x;
    int i = blockIdx.x * 256 + tid;
    int v = (i < N) ? counts[i] : 0;
    s[tid] = v;
    __syncthreads();
    for (int off = 1; off < 256; off <<= 1) {
        int t = (tid >= off) ? s[tid - off] : 0;
        __syncthreads();
        s[tid] += t;
        __syncthreads();
    }
    int incl = s[tid];
    int base = boff[blockIdx.x];
    if (i < N) {
        int excl = base + incl - v;
        row_ptr[i] = excl;
        cursor[i] = excl;
        if (i == N - 1) row_ptr[N] = base + incl;
    }
}

__global__ __launch_bounds__(256) void k_place(const int* __restrict__ src,
                                               const int* __restrict__ dst, int E,
                                               int* __restrict__ cursor,
                                               int* __restrict__ sorted_src) {
    int e = blockIdx.x * 256 + threadIdx.x;
    if (e < E) {
        int d = dst[e];
        int pos = atomicAdd(&cursor[d], 1);
        sorted_src[pos] = src[e];
    }
}

// out[n][c] = dinv[n] * sum_k in[n][k]*W[k][c]   (N x 128) @ (128 x 128)
__global__ __launch_bounds__(256) void k_gemm_scale(const float* __restrict__ in,
                                                    const float* __restrict__ W,
                                                    const float* __restrict__ dinv, int N,
                                                    float* __restrict__ out) {
    __shared__ float Ws[32][128];
    __shared__ float Xs[32][64];
    int tid = threadIdx.x;
    int row0 = blockIdx.x * 64;
    int tc = tid & 15;   // 16 col groups x 8 cols
    int tr = tid >> 4;   // 16 row groups x 4 rows
    float acc[4][8];
#pragma unroll
    for (int i = 0; i < 4; i++)
#pragma unroll
        for (int j = 0; j < 8; j++) acc[i][j] = 0.f;

    for (int k0 = 0; k0 < 128; k0 += 32) {
#pragma unroll
        for (int j = 0; j < 4; j++) {  // stage W chunk: 32x128 = 1024 float4
            int u = tid + j * 256;
            int kk = u >> 5, c4 = u & 31;
            *(float4*)&Ws[kk][c4 * 4] = *(const float4*)&W[(k0 + kk) * 128 + c4 * 4];
        }
#pragma unroll
        for (int j = 0; j < 2; j++) {  // stage X chunk transposed: 64 rows x 32 k
            int u = tid + j * 256;     // 512 float4 units
            int r = u >> 3, kq = u & 7;
            int row = row0 + r;
            if (row > N - 1) row = N - 1;
            float4 v = *(const float4*)&in[(size_t)row * 128 + k0 + kq * 4];
            Xs[kq * 4 + 0][r] = v.x;
            Xs[kq * 4 + 1][r] = v.y;
            Xs[kq * 4 + 2][r] = v.z;
            Xs[kq * 4 + 3][r] = v.w;
        }
        __syncthreads();
#pragma unroll 8
        for (int kk = 0; kk < 32; kk++) {
            float4 xv = *(const float4*)&Xs[kk][tr * 4];
            float4 wa = *(const float4*)&Ws[kk][tc * 8];
            float4 wb = *(const float4*)&Ws[kk][tc * 8 + 4];
            float xr[4] = {xv.x, xv.y, xv.z, xv.w};
            float wc[8] = {wa.x, wa.y, wa.z, wa.w, wb.x, wb.y, wb.z, wb.w};
#pragma unroll
            for (int i = 0; i < 4; i++)
#pragma unroll
                for (int j = 0; j < 8; j++) acc[i][j] += xr[i] * wc[j];
        }
        __syncthreads();
    }
#pragma unroll
    for (int i = 0; i < 4; i++) {
        int row = row0 + tr * 4 + i;
        if (row < N) {
            float di = dinv[row];
            float4 o0 = {di * acc[i][0], di * acc[i][1], di * acc[i][2], di * acc[i][3]};
            float4 o1 = {di * acc[i][4], di * acc[i][5], di * acc[i][6], di * acc[i][7]};
            *(float4*)&out[(size_t)row * 128 + tc * 8] = o0;
            *(float4*)&out[(size_t)row * 128 + tc * 8 + 4] = o1;
        }
    }
}

// one wave per node; float2 per lane; acc = self + sum(incoming); out = relu(dinv*acc + b)
__global__ __launch_bounds__(256) void k_agg128(const float* __restrict__ hs,
                                                const int* __restrict__ row_ptr,
                                                const int* __restrict__ ss,
                                                const float* __restrict__ dinv,
                                                const float* __restrict__ bias, int N,
                                                int do_relu, float* __restrict__ out) {
    int wid = threadIdx.x >> 6;
    int lane = threadIdx.x & 63;
    int node = blockIdx.x * 4 + wid;
    if (node >= N) return;
    int c = lane * 2;
    float2 acc = *(const float2*)&hs[(size_t)node * 128 + c];  // self-loop term
    int s = row_ptr[node], e = row_ptr[node + 1];
    int i = s;
    for (; i + 2 <= e; i += 2) {
        int s0 = ss[i], s1 = ss[i + 1];
        float2 v0 = *(const float2*)&hs[(size_t)s0 * 128 + c];
        float2 v1 = *(const float2*)&hs[(size_t)s1 * 128 + c];
        acc.x += v0.x + v1.x;
        acc.y += v0.y + v1.y;
    }
    if (i < e) {
        int s0 = ss[i];
        float2 v0 = *(const float2*)&hs[(size_t)s0 * 128 + c];
        acc.x += v0.x;
        acc.y += v0.y;
    }
    float di = dinv[node];
    float2 b = *(const float2*)&bias[c];
    float ox = di * acc.x + b.x;
    float oy = di * acc.y + b.y;
    if (do_relu) {
        ox = fmaxf(ox, 0.f);
        oy = fmaxf(oy, 0.f);
    }
    *(float2*)&out[(size_t)node * 128 + c] = {ox, oy};
}

// heads: ths[n][j] = dinv[n] * sum_k h[n][k] * Wcat[k][j], Wcat = [W_age|W_sex|W_eth]
__global__ __launch_bounds__(256) void k_headgemm(const float* __restrict__ h,
                                                  const float* __restrict__ Wa,
                                                  const float* __restrict__ Wsx,
                                                  const float* __restrict__ We,
                                                  const float* __restrict__ dinv, int N,
                                                  float* __restrict__ ths) {
    __shared__ float Ws8[128][8];
    int tid = threadIdx.x;
#pragma unroll
    for (int j = 0; j < 4; j++) {
        int u = tid + j * 256;  // 1024 entries
        int k = u >> 3, c = u & 7;
        float v;
        if (c < 3) v = Wa[k * 3 + c];
        else if (c < 5) v = Wsx[k * 2 + (c - 3)];
        else v = We[k * 3 + (c - 5)];
        Ws8[k][c] = v;
    }
    __syncthreads();
    int node = blockIdx.x * 32 + (tid >> 3);
    int col = tid & 7;
    if (node >= N) return;
    const float* hr = &h[(size_t)node * 128];
    float acc = 0.f;
#pragma unroll 4
    for (int k = 0; k < 128; k += 4) {
        float4 hv = *(const float4*)&hr[k];
        acc += hv.x * Ws8[k][col] + hv.y * Ws8[k + 1][col] + hv.z * Ws8[k + 2][col] +
               hv.w * Ws8[k + 3][col];
    }
    ths[(size_t)node * 8 + col] = dinv[node] * acc;
}

__global__ __launch_bounds__(256) void k_agg8(const float* __restrict__ ths,
                                              const int* __restrict__ row_ptr,
                                              const int* __restrict__ ss,
                                              const float* __restrict__ dinv,
                                              const float* __restrict__ ba,
                                              const float* __restrict__ bs,
                                              const float* __restrict__ be, int N,
                                              float* __restrict__ outp) {
    int tid = threadIdx.x;
    int node = blockIdx.x * 32 + (tid >> 3);
    int j = tid & 7;
    if (node >= N) return;
    float acc = ths[(size_t)node * 8 + j];  // self
    int s = row_ptr[node], e = row_ptr[node + 1];
    for (int i = s; i < e; i++) {
        int sc = ss[i];
        acc += ths[(size_t)sc * 8 + j];
    }
    float bias = (j < 3) ? ba[j] : ((j < 5) ? bs[j - 3] : be[j - 5]);
    float v = dinv[node] * acc + bias;
    if (j < 3) outp[(size_t)node * 3 + j] = v;
    else if (j < 5) outp[(size_t)N * 3 + (size_t)node * 2 + (j - 3)] = v;
    else outp[(size_t)N * 5 + (size_t)node * 3 + (j - 5)] = v;
}

extern "C" void kernel_launch(void* const* d_in, const int* in_sizes, int n_in,
                              void* d_out, int out_size, void* d_ws, size_t ws_size,
                              hipStream_t stream) {
    const float* x = (const float*)d_in[0];
    const int* edge = (const int*)d_in[1];
    const float* W1 = (const float*)d_in[2];
    const float* b1 = (const float*)d_in[3];
    const float* W2 = (const float*)d_in[4];
    const float* b2 = (const float*)d_in[5];
    const float* Wa = (const float*)d_in[6];
    const float* ba = (const float*)d_in[7];
    const float* Wsx = (const float*)d_in[8];
    const float* bs = (const float*)d_in[9];
    const float* We = (const float*)d_in[10];
    const float* be = (const float*)d_in[11];

    int N = in_sizes[0] / 128;
    int E = in_sizes[1] / 2;
    const int* srcp = edge;
    const int* dstp = edge + E;

    char* ws = (char*)d_ws;
    size_t off = 0;
    auto alloc = [&](size_t bytes) -> char* {
        char* p = ws + off;
        off += (bytes + 255) & ~(size_t)255;
        return p;
    };
    int* counts = (int*)alloc((size_t)N * 4);
    float* dinv = (float*)alloc((size_t)N * 4);
    int* row_ptr = (int*)alloc((size_t)(N + 1) * 4);
    int* cursor = (int*)alloc((size_t)N * 4);
    int* bsum = (int*)alloc(4096);
    int* boff = (int*)alloc(4096);
    int* sorted = (int*)alloc((size_t)E * 4);
    float* bufA = (float*)alloc((size_t)N * 128 * 4);
    float* bufB = (float*)alloc((size_t)N * 128 * 4);

    int nbE = (E + 255) / 256;
    int nbN = (N + 255) / 256;

    hipMemsetAsync(counts, 0, (size_t)N * 4, stream);
    k_count<<<nbE, 256, 0, stream>>>(dstp, E, counts);
    k_dinv<<<nbN, 256, 0, stream>>>(counts, N, dinv);
    k_scanA<<<nbN, 256, 0, stream>>>(counts, N, bsum);
    k_scanB<<<1, 256, 0, stream>>>(bsum, nbN, boff);
    k_scanC<<<nbN, 256, 0, stream>>>(counts, N, boff, row_ptr, cursor);
    k_place<<<nbE, 256, 0, stream>>>(srcp, dstp, E, cursor, sorted);

    int gb = (N + 63) / 64;
    k_gemm_scale<<<gb, 256, 0, stream>>>(x, W1, dinv, N, bufA);
    k_agg128<<<(N + 3) / 4, 256, 0, stream>>>(bufA, row_ptr, sorted, dinv, b1, N, 1, bufB);
    k_gemm_scale<<<gb, 256, 0, stream>>>(bufB, W2, dinv, N, bufA);
    k_agg128<<<(N + 3) / 4, 256, 0, stream>>>(bufA, row_ptr, sorted, dinv, b2, N, 1, bufB);
    k_headgemm<<<(N + 31) / 32, 256, 0, stream>>>(bufB, Wa, Wsx, We, dinv, N, bufA);
    k_agg8<<<(N + 31) / 32, 256, 0, stream>>>(bufA, row_ptr, sorted, dinv, ba, bs, be, N,
                                              (float*)d_out);
}

// Round 2
// 379.725 us; speedup vs baseline: 1.4155x; 1.4155x over previous
//
#include <hip/hip_runtime.h>

// GCN: out = dinv ⊙ ( A_sum ( dinv ⊙ (x@W) ) ) + b, A_sum includes self-loop.
// CSR (by dst) built on-device each call via bucketed multi-split (LDS atomics only
// on the hot path); pull-based aggregation, sorted_src stored as uint16 (N < 65536).

#define NBUK_MAX 512  // buckets of 128 nodes; N=50000 -> 391 buckets

// Pass 0: per-bucket edge histogram (LDS hist, one global atomic per block*bucket)
__global__ __launch_bounds__(256) void k_bhist(const int* __restrict__ dst, int E, int nbuk,
                                               int* __restrict__ bcount) {
    __shared__ int h[NBUK_MAX];
    int tid = threadIdx.x;
    for (int i = tid; i < nbuk; i += 256) h[i] = 0;
    __syncthreads();
    int s0 = blockIdx.x * 4096;
#pragma unroll
    for (int i = 0; i < 16; i++) {
        int e = s0 + i * 256 + tid;
        if (e < E) atomicAdd(&h[dst[e] >> 7], 1);
    }
    __syncthreads();
    for (int i = tid; i < nbuk; i += 256)
        if (h[i]) atomicAdd(&bcount[i], h[i]);
}

// scan bucket counts -> bbase (exclusive, [nbuk+1]) and bcur (working copy)
__global__ __launch_bounds__(512) void k_bscan(const int* __restrict__ bcount, int nb,
                                               int* __restrict__ bbase, int* __restrict__ bcur) {
    __shared__ int s[512];
    int tid = threadIdx.x;
    int v = (tid < nb) ? bcount[tid] : 0;
    s[tid] = v;
    __syncthreads();
    for (int off = 1; off < 512; off <<= 1) {
        int t = (tid >= off) ? s[tid - off] : 0;
        __syncthreads();
        s[tid] += t;
        __syncthreads();
    }
    if (tid < nb) {
        int excl = s[tid] - v;
        bbase[tid] = excl;
        bcur[tid] = excl;
        if (tid == nb - 1) bbase[nb] = s[tid];
    }
}

// Pass A: multi-split edges into bucket regions; packed entry (dst<<16)|src
__global__ __launch_bounds__(256) void k_passA(const int* __restrict__ src,
                                               const int* __restrict__ dst, int E, int nbuk,
                                               int* __restrict__ bcur,
                                               unsigned* __restrict__ bbuf) {
    __shared__ int h[NBUK_MAX];
    __shared__ int base[NBUK_MAX];
    __shared__ int lcur[NBUK_MAX];
    int tid = threadIdx.x;
    for (int i = tid; i < nbuk; i += 256) h[i] = 0;
    __syncthreads();
    int s0 = blockIdx.x * 4096;
#pragma unroll
    for (int i = 0; i < 16; i++) {
        int e = s0 + i * 256 + tid;
        if (e < E) atomicAdd(&h[dst[e] >> 7], 1);
    }
    __syncthreads();
    for (int i = tid; i < nbuk; i += 256) {
        int c = h[i];
        base[i] = c ? atomicAdd(&bcur[i], c) : 0;
        lcur[i] = 0;
    }
    __syncthreads();
#pragma unroll
    for (int i = 0; i < 16; i++) {
        int e = s0 + i * 256 + tid;
        if (e < E) {
            int d = dst[e];
            int b = d >> 7;
            int idx = atomicAdd(&lcur[b], 1);
            bbuf[base[b] + idx] = ((unsigned)d << 16) | (unsigned)src[e];
        }
    }
}

// Pass B: one block per bucket. LDS hist+scan over 128 nodes -> row_ptr, dinv,
// final placement of src (uint16) with LDS cursors only.
__global__ __launch_bounds__(256) void k_passB(const unsigned* __restrict__ bbuf,
                                               const int* __restrict__ bbase, int N,
                                               int* __restrict__ row_ptr,
                                               float* __restrict__ dinv,
                                               unsigned short* __restrict__ sorted) {
    __shared__ int h[128], sc[128], lc[128];
    int b = blockIdx.x, tid = threadIdx.x;
    int node0 = b << 7;
    int ncnt = min(128, N - node0);
    int s = bbase[b], e = bbase[b + 1];
    if (tid < 128) h[tid] = 0;
    __syncthreads();
    for (int i = s + tid; i < e; i += 256) atomicAdd(&h[(bbuf[i] >> 16) & 127], 1);
    __syncthreads();
    if (tid < 128) sc[tid] = h[tid];
    __syncthreads();
    for (int off = 1; off < 128; off <<= 1) {
        int t = 0;
        if (tid < 128 && tid >= off) t = sc[tid - off];
        __syncthreads();
        if (tid < 128) sc[tid] += t;
        __syncthreads();
    }
    if (tid < ncnt) {
        int excl = sc[tid] - h[tid];
        row_ptr[node0 + tid] = s + excl;
        dinv[node0 + tid] = rsqrtf((float)(h[tid] + 1));  // +1 self-loop
        lc[tid] = excl;
    }
    if (b == gridDim.x - 1 && tid == 0) row_ptr[N] = e;
    __syncthreads();
    for (int i = s + tid; i < e; i += 256) {
        unsigned p = bbuf[i];
        int nl = (p >> 16) & 127;
        int idx = atomicAdd(&lc[nl], 1);
        sorted[s + idx] = (unsigned short)(p & 0xffffu);
    }
}

// out[n][c] = dinv[n] * sum_k in[n][k]*W[k][c]   (N x 128) @ (128 x 128)
__global__ __launch_bounds__(256) void k_gemm_scale(const float* __restrict__ in,
                                                    const float* __restrict__ W,
                                                    const float* __restrict__ dinv, int N,
                                                    float* __restrict__ out) {
    __shared__ float Ws[32][128];
    __shared__ float Xs[32][64];
    int tid = threadIdx.x;
    int row0 = blockIdx.x * 64;
    int tc = tid & 15;   // 16 col groups x 8 cols
    int tr = tid >> 4;   // 16 row groups x 4 rows
    float acc[4][8];
#pragma unroll
    for (int i = 0; i < 4; i++)
#pragma unroll
        for (int j = 0; j < 8; j++) acc[i][j] = 0.f;

    for (int k0 = 0; k0 < 128; k0 += 32) {
#pragma unroll
        for (int j = 0; j < 4; j++) {  // stage W chunk: 32x128 = 1024 float4
            int u = tid + j * 256;
            int kk = u >> 5, c4 = u & 31;
            *(float4*)&Ws[kk][c4 * 4] = *(const float4*)&W[(k0 + kk) * 128 + c4 * 4];
        }
#pragma unroll
        for (int j = 0; j < 2; j++) {  // stage X chunk transposed: 64 rows x 32 k
            int u = tid + j * 256;     // 512 float4 units
            int r = u >> 3, kq = u & 7;
            int row = row0 + r;
            if (row > N - 1) row = N - 1;
            float4 v = *(const float4*)&in[(size_t)row * 128 + k0 + kq * 4];
            Xs[kq * 4 + 0][r] = v.x;
            Xs[kq * 4 + 1][r] = v.y;
            Xs[kq * 4 + 2][r] = v.z;
            Xs[kq * 4 + 3][r] = v.w;
        }
        __syncthreads();
#pragma unroll 8
        for (int kk = 0; kk < 32; kk++) {
            float4 xv = *(const float4*)&Xs[kk][tr * 4];
            float4 wa = *(const float4*)&Ws[kk][tc * 8];
            float4 wb = *(const float4*)&Ws[kk][tc * 8 + 4];
            float xr[4] = {xv.x, xv.y, xv.z, xv.w};
            float wc[8] = {wa.x, wa.y, wa.z, wa.w, wb.x, wb.y, wb.z, wb.w};
#pragma unroll
            for (int i = 0; i < 4; i++)
#pragma unroll
                for (int j = 0; j < 8; j++) acc[i][j] += xr[i] * wc[j];
        }
        __syncthreads();
    }
#pragma unroll
    for (int i = 0; i < 4; i++) {
        int row = row0 + tr * 4 + i;
        if (row < N) {
            float di = dinv[row];
            float4 o0 = {di * acc[i][0], di * acc[i][1], di * acc[i][2], di * acc[i][3]};
            float4 o1 = {di * acc[i][4], di * acc[i][5], di * acc[i][6], di * acc[i][7]};
            *(float4*)&out[(size_t)row * 128 + tc * 8] = o0;
            *(float4*)&out[(size_t)row * 128 + tc * 8 + 4] = o1;
        }
    }
}

// one wave per node; float2 per lane; acc = self + sum(incoming); out = relu(dinv*acc + b)
__global__ __launch_bounds__(256) void k_agg128(const float* __restrict__ hs,
                                                const int* __restrict__ row_ptr,
                                                const unsigned short* __restrict__ ss,
                                                const float* __restrict__ dinv,
                                                const float* __restrict__ bias, int N,
                                                int do_relu, float* __restrict__ out) {
    int wid = threadIdx.x >> 6;
    int lane = threadIdx.x & 63;
    int node = blockIdx.x * 4 + wid;
    if (node >= N) return;
    int c = lane * 2;
    float2 acc = *(const float2*)&hs[(size_t)node * 128 + c];  // self-loop term
    int s = row_ptr[node], e = row_ptr[node + 1];
    int i = s;
    for (; i + 2 <= e; i += 2) {
        int s0 = ss[i], s1 = ss[i + 1];
        float2 v0 = *(const float2*)&hs[(size_t)s0 * 128 + c];
        float2 v1 = *(const float2*)&hs[(size_t)s1 * 128 + c];
        acc.x += v0.x + v1.x;
        acc.y += v0.y + v1.y;
    }
    if (i < e) {
        int s0 = ss[i];
        float2 v0 = *(const float2*)&hs[(size_t)s0 * 128 + c];
        acc.x += v0.x;
        acc.y += v0.y;
    }
    float di = dinv[node];
    float2 b = *(const float2*)&bias[c];
    float ox = di * acc.x + b.x;
    float oy = di * acc.y + b.y;
    if (do_relu) {
        ox = fmaxf(ox, 0.f);
        oy = fmaxf(oy, 0.f);
    }
    *(float2*)&out[(size_t)node * 128 + c] = {ox, oy};
}

// heads: ths[n][j] = dinv[n] * sum_k h[n][k] * Wcat[k][j], Wcat = [W_age|W_sex|W_eth]
__global__ __launch_bounds__(256) void k_headgemm(const float* __restrict__ h,
                                                  const float* __restrict__ Wa,
                                                  const float* __restrict__ Wsx,
                                                  const float* __restrict__ We,
                                                  const float* __restrict__ dinv, int N,
                                                  float* __restrict__ ths) {
    __shared__ float Ws8[128][8];
    int tid = threadIdx.x;
#pragma unroll
    for (int j = 0; j < 4; j++) {
        int u = tid + j * 256;  // 1024 entries
        int k = u >> 3, c = u & 7;
        float v;
        if (c < 3) v = Wa[k * 3 + c];
        else if (c < 5) v = Wsx[k * 2 + (c - 3)];
        else v = We[k * 3 + (c - 5)];
        Ws8[k][c] = v;
    }
    __syncthreads();
    int node = blockIdx.x * 32 + (tid >> 3);
    int col = tid & 7;
    if (node >= N) return;
    const float* hr = &h[(size_t)node * 128];
    float acc = 0.f;
#pragma unroll 4
    for (int k = 0; k < 128; k += 4) {
        float4 hv = *(const float4*)&hr[k];
        acc += hv.x * Ws8[k][col] + hv.y * Ws8[k + 1][col] + hv.z * Ws8[k + 2][col] +
               hv.w * Ws8[k + 3][col];
    }
    ths[(size_t)node * 8 + col] = dinv[node] * acc;
}

__global__ __launch_bounds__(256) void k_agg8(const float* __restrict__ ths,
                                              const int* __restrict__ row_ptr,
                                              const unsigned short* __restrict__ ss,
                                              const float* __restrict__ dinv,
                                              const float* __restrict__ ba,
                                              const float* __restrict__ bs,
                                              const float* __restrict__ be, int N,
                                              float* __restrict__ outp) {
    int tid = threadIdx.x;
    int node = blockIdx.x * 32 + (tid >> 3);
    int j = tid & 7;
    if (node >= N) return;
    float acc = ths[(size_t)node * 8 + j];  // self
    int s = row_ptr[node], e = row_ptr[node + 1];
    for (int i = s; i < e; i++) {
        int sc = ss[i];
        acc += ths[(size_t)sc * 8 + j];
    }
    float bias = (j < 3) ? ba[j] : ((j < 5) ? bs[j - 3] : be[j - 5]);
    float v = dinv[node] * acc + bias;
    if (j < 3) outp[(size_t)node * 3 + j] = v;
    else if (j < 5) outp[(size_t)N * 3 + (size_t)node * 2 + (j - 3)] = v;
    else outp[(size_t)N * 5 + (size_t)node * 3 + (j - 5)] = v;
}

extern "C" void kernel_launch(void* const* d_in, const int* in_sizes, int n_in,
                              void* d_out, int out_size, void* d_ws, size_t ws_size,
                              hipStream_t stream) {
    const float* x = (const float*)d_in[0];
    const int* edge = (const int*)d_in[1];
    const float* W1 = (const float*)d_in[2];
    const float* b1 = (const float*)d_in[3];
    const float* W2 = (const float*)d_in[4];
    const float* b2 = (const float*)d_in[5];
    const float* Wa = (const float*)d_in[6];
    const float* ba = (const float*)d_in[7];
    const float* Wsx = (const float*)d_in[8];
    const float* bs = (const float*)d_in[9];
    const float* We = (const float*)d_in[10];
    const float* be = (const float*)d_in[11];

    int N = in_sizes[0] / 128;
    int E = in_sizes[1] / 2;
    const int* srcp = edge;
    const int* dstp = edge + E;
    int nbuk = (N + 127) >> 7;

    char* ws = (char*)d_ws;
    size_t off = 0;
    auto alloc = [&](size_t bytes) -> char* {
        char* p = ws + off;
        off += (bytes + 255) & ~(size_t)255;
        return p;
    };
    int* bcount = (int*)alloc((size_t)(nbuk + 1) * 4);
    int* bbase = (int*)alloc((size_t)(nbuk + 1) * 4);
    int* bcur = (int*)alloc((size_t)(nbuk + 1) * 4);
    int* row_ptr = (int*)alloc((size_t)(N + 1) * 4);
    float* dinv = (float*)alloc((size_t)N * 4);
    unsigned* bbuf = (unsigned*)alloc((size_t)E * 4);
    unsigned short* sorted = (unsigned short*)alloc((size_t)E * 2);
    float* bufA = (float*)alloc((size_t)N * 128 * 4);
    float* bufB = (float*)alloc((size_t)N * 128 * 4);

    int nbT = (E + 4095) / 4096;

    hipMemsetAsync(bcount, 0, (size_t)(nbuk + 1) * 4, stream);
    k_bhist<<<nbT, 256, 0, stream>>>(dstp, E, nbuk, bcount);
    k_bscan<<<1, 512, 0, stream>>>(bcount, nbuk, bbase, bcur);
    k_passA<<<nbT, 256, 0, stream>>>(srcp, dstp, E, nbuk, bcur, bbuf);
    k_passB<<<nbuk, 256, 0, stream>>>(bbuf, bbase, N, row_ptr, dinv, sorted);

    int gb = (N + 63) / 64;
    k_gemm_scale<<<gb, 256, 0, stream>>>(x, W1, dinv, N, bufA);
    k_agg128<<<(N + 3) / 4, 256, 0, stream>>>(bufA, row_ptr, sorted, dinv, b1, N, 1, bufB);
    k_gemm_scale<<<gb, 256, 0, stream>>>(bufB, W2, dinv, N, bufA);
    k_agg128<<<(N + 3) / 4, 256, 0, stream>>>(bufA, row_ptr, sorted, dinv, b2, N, 1, bufB);
    k_headgemm<<<(N + 31) / 32, 256, 0, stream>>>(bufB, Wa, Wsx, We, dinv, N, bufA);
    k_agg8<<<(N + 31) / 32, 256, 0, stream>>>(bufA, row_ptr, sorted, dinv, ba, bs, be, N,
                                              (float*)d_out);
}

// Round 3
// 274.514 us; speedup vs baseline: 1.9580x; 1.3833x over previous
//
#include <hip/hip_runtime.h>
#include <hip/hip_fp16.h>

// GCN: out = dinv ⊙ ( A_sum ( dinv ⊙ (x@W) ) ) + b, A_sum includes self-loop.
// CSR (by dst) built on-device via bucketed multi-split (LDS atomics on hot path).
// Pull aggregation gathers an fp16 copy of hs (halves gather traffic + working set);
// accumulation and outputs stay fp32. sorted_src stored as uint16 (N < 65536).

#define NBUK_MAX 512  // buckets of 128 nodes; N=50000 -> 391 buckets

__global__ __launch_bounds__(256) void k_bhist(const int* __restrict__ dst, int E, int nbuk,
                                               int* __restrict__ bcount) {
    __shared__ int h[NBUK_MAX];
    int tid = threadIdx.x;
    for (int i = tid; i < nbuk; i += 256) h[i] = 0;
    __syncthreads();
    int s0 = blockIdx.x * 4096;
#pragma unroll
    for (int i = 0; i < 16; i++) {
        int e = s0 + i * 256 + tid;
        if (e < E) atomicAdd(&h[dst[e] >> 7], 1);
    }
    __syncthreads();
    for (int i = tid; i < nbuk; i += 256)
        if (h[i]) atomicAdd(&bcount[i], h[i]);
}

__global__ __launch_bounds__(512) void k_bscan(const int* __restrict__ bcount, int nb,
                                               int* __restrict__ bbase, int* __restrict__ bcur) {
    __shared__ int s[512];
    int tid = threadIdx.x;
    int v = (tid < nb) ? bcount[tid] : 0;
    s[tid] = v;
    __syncthreads();
    for (int off = 1; off < 512; off <<= 1) {
        int t = (tid >= off) ? s[tid - off] : 0;
        __syncthreads();
        s[tid] += t;
        __syncthreads();
    }
    if (tid < nb) {
        int excl = s[tid] - v;
        bbase[tid] = excl;
        bcur[tid] = excl;
        if (tid == nb - 1) bbase[nb] = s[tid];
    }
}

__global__ __launch_bounds__(256) void k_passA(const int* __restrict__ src,
                                               const int* __restrict__ dst, int E, int nbuk,
                                               int* __restrict__ bcur,
                                               unsigned* __restrict__ bbuf) {
    __shared__ int h[NBUK_MAX];
    __shared__ int base[NBUK_MAX];
    __shared__ int lcur[NBUK_MAX];
    int tid = threadIdx.x;
    for (int i = tid; i < nbuk; i += 256) h[i] = 0;
    __syncthreads();
    int s0 = blockIdx.x * 4096;
#pragma unroll
    for (int i = 0; i < 16; i++) {
        int e = s0 + i * 256 + tid;
        if (e < E) atomicAdd(&h[dst[e] >> 7], 1);
    }
    __syncthreads();
    for (int i = tid; i < nbuk; i += 256) {
        int c = h[i];
        base[i] = c ? atomicAdd(&bcur[i], c) : 0;
        lcur[i] = 0;
    }
    __syncthreads();
#pragma unroll
    for (int i = 0; i < 16; i++) {
        int e = s0 + i * 256 + tid;
        if (e < E) {
            int d = dst[e];
            int b = d >> 7;
            int idx = atomicAdd(&lcur[b], 1);
            bbuf[base[b] + idx] = ((unsigned)d << 16) | (unsigned)src[e];
        }
    }
}

__global__ __launch_bounds__(256) void k_passB(const unsigned* __restrict__ bbuf,
                                               const int* __restrict__ bbase, int N,
                                               int* __restrict__ row_ptr,
                                               float* __restrict__ dinv,
                                               unsigned short* __restrict__ sorted) {
    __shared__ int h[128], sc[128], lc[128];
    int b = blockIdx.x, tid = threadIdx.x;
    int node0 = b << 7;
    int ncnt = min(128, N - node0);
    int s = bbase[b], e = bbase[b + 1];
    if (tid < 128) h[tid] = 0;
    __syncthreads();
    for (int i = s + tid; i < e; i += 256) atomicAdd(&h[(bbuf[i] >> 16) & 127], 1);
    __syncthreads();
    if (tid < 128) sc[tid] = h[tid];
    __syncthreads();
    for (int off = 1; off < 128; off <<= 1) {
        int t = 0;
        if (tid < 128 && tid >= off) t = sc[tid - off];
        __syncthreads();
        if (tid < 128) sc[tid] += t;
        __syncthreads();
    }
    if (tid < ncnt) {
        int excl = sc[tid] - h[tid];
        row_ptr[node0 + tid] = s + excl;
        dinv[node0 + tid] = rsqrtf((float)(h[tid] + 1));  // +1 self-loop
        lc[tid] = excl;
    }
    if (b == gridDim.x - 1 && tid == 0) row_ptr[N] = e;
    __syncthreads();
    for (int i = s + tid; i < e; i += 256) {
        unsigned p = bbuf[i];
        int nl = (p >> 16) & 127;
        int idx = atomicAdd(&lc[nl], 1);
        sorted[s + idx] = (unsigned short)(p & 0xffffu);
    }
}

// out[n][c] = (half) dinv[n] * sum_k in[n][k]*W[k][c]   (N x 128) @ (128 x 128)
__global__ __launch_bounds__(256) void k_gemm_scale_h(const float* __restrict__ in,
                                                      const float* __restrict__ W,
                                                      const float* __restrict__ dinv, int N,
                                                      __half* __restrict__ out) {
    __shared__ float Ws[32][128];
    __shared__ float Xs[32][64];
    int tid = threadIdx.x;
    int row0 = blockIdx.x * 64;
    int tc = tid & 15;   // 16 col groups x 8 cols
    int tr = tid >> 4;   // 16 row groups x 4 rows
    float acc[4][8];
#pragma unroll
    for (int i = 0; i < 4; i++)
#pragma unroll
        for (int j = 0; j < 8; j++) acc[i][j] = 0.f;

    for (int k0 = 0; k0 < 128; k0 += 32) {
#pragma unroll
        for (int j = 0; j < 4; j++) {  // stage W chunk: 32x128 = 1024 float4
            int u = tid + j * 256;
            int kk = u >> 5, c4 = u & 31;
            *(float4*)&Ws[kk][c4 * 4] = *(const float4*)&W[(k0 + kk) * 128 + c4 * 4];
        }
#pragma unroll
        for (int j = 0; j < 2; j++) {  // stage X chunk transposed: 64 rows x 32 k
            int u = tid + j * 256;     // 512 float4 units
            int r = u >> 3, kq = u & 7;
            int row = row0 + r;
            if (row > N - 1) row = N - 1;
            float4 v = *(const float4*)&in[(size_t)row * 128 + k0 + kq * 4];
            Xs[kq * 4 + 0][r] = v.x;
            Xs[kq * 4 + 1][r] = v.y;
            Xs[kq * 4 + 2][r] = v.z;
            Xs[kq * 4 + 3][r] = v.w;
        }
        __syncthreads();
#pragma unroll 8
        for (int kk = 0; kk < 32; kk++) {
            float4 xv = *(const float4*)&Xs[kk][tr * 4];
            float4 wa = *(const float4*)&Ws[kk][tc * 8];
            float4 wb = *(const float4*)&Ws[kk][tc * 8 + 4];
            float xr[4] = {xv.x, xv.y, xv.z, xv.w};
            float wc[8] = {wa.x, wa.y, wa.z, wa.w, wb.x, wb.y, wb.z, wb.w};
#pragma unroll
            for (int i = 0; i < 4; i++)
#pragma unroll
                for (int j = 0; j < 8; j++) acc[i][j] += xr[i] * wc[j];
        }
        __syncthreads();
    }
#pragma unroll
    for (int i = 0; i < 4; i++) {
        int row = row0 + tr * 4 + i;
        if (row < N) {
            float di = dinv[row];
            union {
                uint4 u;
                __half h[8];
            } pk;
#pragma unroll
            for (int j = 0; j < 8; j++) pk.h[j] = __float2half_rn(di * acc[i][j]);
            *(uint4*)&out[(size_t)row * 128 + tc * 8] = pk.u;
        }
    }
}

// one wave per node; half2 (2 cols) per lane; fp32 accumulate; out = relu(dinv*acc + b)
__global__ __launch_bounds__(256) void k_agg128h(const __half* __restrict__ hs,
                                                 const int* __restrict__ row_ptr,
                                                 const unsigned short* __restrict__ ss,
                                                 const float* __restrict__ dinv,
                                                 const float* __restrict__ bias, int N,
                                                 int do_relu, float* __restrict__ out) {
    int wid = threadIdx.x >> 6;
    int lane = threadIdx.x & 63;
    int node = blockIdx.x * 4 + wid;
    if (node >= N) return;
    const __half2* hp = (const __half2*)hs;  // row stride 64 half2
    float2 acc = __half22float2(hp[(size_t)node * 64 + lane]);  // self-loop term
    int s = row_ptr[node], e = row_ptr[node + 1];
    int i = s;
    for (; i + 4 <= e; i += 4) {
        int s0 = ss[i], s1 = ss[i + 1], s2 = ss[i + 2], s3 = ss[i + 3];
        float2 v0 = __half22float2(hp[(size_t)s0 * 64 + lane]);
        float2 v1 = __half22float2(hp[(size_t)s1 * 64 + lane]);
        float2 v2 = __half22float2(hp[(size_t)s2 * 64 + lane]);
        float2 v3 = __half22float2(hp[(size_t)s3 * 64 + lane]);
        acc.x += (v0.x + v1.x) + (v2.x + v3.x);
        acc.y += (v0.y + v1.y) + (v2.y + v3.y);
    }
    for (; i < e; i++) {
        float2 v0 = __half22float2(hp[(size_t)ss[i] * 64 + lane]);
        acc.x += v0.x;
        acc.y += v0.y;
    }
    float di = dinv[node];
    int c = lane * 2;
    float2 b = *(const float2*)&bias[c];
    float ox = di * acc.x + b.x;
    float oy = di * acc.y + b.y;
    if (do_relu) {
        ox = fmaxf(ox, 0.f);
        oy = fmaxf(oy, 0.f);
    }
    *(float2*)&out[(size_t)node * 128 + c] = {ox, oy};
}

// heads: ths[n][j] = dinv[n] * sum_k h[n][k] * Wcat[k][j], Wcat = [W_age|W_sex|W_eth]
__global__ __launch_bounds__(256) void k_headgemm(const float* __restrict__ h,
                                                  const float* __restrict__ Wa,
                                                  const float* __restrict__ Wsx,
                                                  const float* __restrict__ We,
                                                  const float* __restrict__ dinv, int N,
                                                  float* __restrict__ ths) {
    __shared__ float Ws8[128][8];
    int tid = threadIdx.x;
#pragma unroll
    for (int j = 0; j < 4; j++) {
        int u = tid + j * 256;  // 1024 entries
        int k = u >> 3, c = u & 7;
        float v;
        if (c < 3) v = Wa[k * 3 + c];
        else if (c < 5) v = Wsx[k * 2 + (c - 3)];
        else v = We[k * 3 + (c - 5)];
        Ws8[k][c] = v;
    }
    __syncthreads();
    int node = blockIdx.x * 32 + (tid >> 3);
    int col = tid & 7;
    if (node >= N) return;
    const float* hr = &h[(size_t)node * 128];
    float acc = 0.f;
#pragma unroll 4
    for (int k = 0; k < 128; k += 4) {
        float4 hv = *(const float4*)&hr[k];
        acc += hv.x * Ws8[k][col] + hv.y * Ws8[k + 1][col] + hv.z * Ws8[k + 2][col] +
               hv.w * Ws8[k + 3][col];
    }
    ths[(size_t)node * 8 + col] = dinv[node] * acc;
}

__global__ __launch_bounds__(256) void k_agg8(const float* __restrict__ ths,
                                              const int* __restrict__ row_ptr,
                                              const unsigned short* __restrict__ ss,
                                              const float* __restrict__ dinv,
                                              const float* __restrict__ ba,
                                              const float* __restrict__ bs,
                                              const float* __restrict__ be, int N,
                                              float* __restrict__ outp) {
    int tid = threadIdx.x;
    int node = blockIdx.x * 32 + (tid >> 3);
    int j = tid & 7;
    if (node >= N) return;
    float acc = ths[(size_t)node * 8 + j];  // self
    int s = row_ptr[node], e = row_ptr[node + 1];
    for (int i = s; i < e; i++) {
        int sc = ss[i];
        acc += ths[(size_t)sc * 8 + j];
    }
    float bias = (j < 3) ? ba[j] : ((j < 5) ? bs[j - 3] : be[j - 5]);
    float v = dinv[node] * acc + bias;
    if (j < 3) outp[(size_t)node * 3 + j] = v;
    else if (j < 5) outp[(size_t)N * 3 + (size_t)node * 2 + (j - 3)] = v;
    else outp[(size_t)N * 5 + (size_t)node * 3 + (j - 5)] = v;
}

extern "C" void kernel_launch(void* const* d_in, const int* in_sizes, int n_in,
                              void* d_out, int out_size, void* d_ws, size_t ws_size,
                              hipStream_t stream) {
    const float* x = (const float*)d_in[0];
    const int* edge = (const int*)d_in[1];
    const float* W1 = (const float*)d_in[2];
    const float* b1 = (const float*)d_in[3];
    const float* W2 = (const float*)d_in[4];
    const float* b2 = (const float*)d_in[5];
    const float* Wa = (const float*)d_in[6];
    const float* ba = (const float*)d_in[7];
    const float* Wsx = (const float*)d_in[8];
    const float* bs = (const float*)d_in[9];
    const float* We = (const float*)d_in[10];
    const float* be = (const float*)d_in[11];

    int N = in_sizes[0] / 128;
    int E = in_sizes[1] / 2;
    const int* srcp = edge;
    const int* dstp = edge + E;
    int nbuk = (N + 127) >> 7;

    char* ws = (char*)d_ws;
    size_t off = 0;
    auto alloc = [&](size_t bytes) -> char* {
        char* p = ws + off;
        off += (bytes + 255) & ~(size_t)255;
        return p;
    };
    int* bcount = (int*)alloc((size_t)(nbuk + 1) * 4);
    int* bbase = (int*)alloc((size_t)(nbuk + 1) * 4);
    int* bcur = (int*)alloc((size_t)(nbuk + 1) * 4);
    int* row_ptr = (int*)alloc((size_t)(N + 1) * 4);
    float* dinv = (float*)alloc((size_t)N * 4);
    unsigned* bbuf = (unsigned*)alloc((size_t)E * 4);
    unsigned short* sorted = (unsigned short*)alloc((size_t)E * 2);
    __half* bufH = (__half*)alloc((size_t)N * 128 * 2);   // fp16 hs (gather operand)
    float* bufF = (float*)alloc((size_t)N * 128 * 4);     // fp32 agg output / gemm input
    float* ths = (float*)alloc((size_t)N * 8 * 4);

    int nbT = (E + 4095) / 4096;

    hipMemsetAsync(bcount, 0, (size_t)(nbuk + 1) * 4, stream);
    k_bhist<<<nbT, 256, 0, stream>>>(dstp, E, nbuk, bcount);
    k_bscan<<<1, 512, 0, stream>>>(bcount, nbuk, bbase, bcur);
    k_passA<<<nbT, 256, 0, stream>>>(srcp, dstp, E, nbuk, bcur, bbuf);
    k_passB<<<nbuk, 256, 0, stream>>>(bbuf, bbase, N, row_ptr, dinv, sorted);

    int gb = (N + 63) / 64;
    k_gemm_scale_h<<<gb, 256, 0, stream>>>(x, W1, dinv, N, bufH);
    k_agg128h<<<(N + 3) / 4, 256, 0, stream>>>(bufH, row_ptr, sorted, dinv, b1, N, 1, bufF);
    k_gemm_scale_h<<<gb, 256, 0, stream>>>(bufF, W2, dinv, N, bufH);
    k_agg128h<<<(N + 3) / 4, 256, 0, stream>>>(bufH, row_ptr, sorted, dinv, b2, N, 1, bufF);
    k_headgemm<<<(N + 31) / 32, 256, 0, stream>>>(bufF, Wa, Wsx, We, dinv, N, ths);
    k_agg8<<<(N + 31) / 32, 256, 0, stream>>>(ths, row_ptr, sorted, dinv, ba, bs, be, N,
                                              (float*)d_out);
}